// Round 2
// baseline (139.217 us; speedup 1.0000x reference)
//
#include <hip/hip_runtime.h>
#include <hip/hip_bf16.h>

#define NN 2048
typedef unsigned short u16;
typedef unsigned long long u64;
typedef __attribute__((ext_vector_type(8))) short short8;
typedef __attribute__((ext_vector_type(4))) float f32x4;

// fp32 -> bf16 bits, RNE (scalar path)
__device__ __forceinline__ unsigned bfb(float x) {
    unsigned u = __float_as_uint(x);
    return (u + 0x7FFFu + ((u >> 16) & 1u)) >> 16;
}
// packed pair via HW cvt (identical RNE bits, 1 instr)
__device__ __forceinline__ unsigned pk2(float a, float b) {
    unsigned r;
    asm("v_cvt_pk_bf16_f32 %0, %1, %2" : "=v"(r) : "v"(a), "v"(b));
    return r;
}

// ---------------- gemm1 (+ fused x/W1 conversion + adj bitmask blocks) ----------------
// grid (128, 10) x 256 thr. y<8: GEMM tile 16 rows x 32 cols (head y), K=512 from LDS.
// y>=8: 256 blocks build adj bitmask (overlaps GEMM compute; consumed by attn1/attn2).
__global__ __launch_bounds__(256) void gemm1(const float* __restrict__ x,   // [2048][512]
                                             const float* __restrict__ W1,  // [512][256]
                                             const int* __restrict__ adj,   // [2048][2048]
                                             const float* __restrict__ al,
                                             const float* __restrict__ ar,
                                             u16* __restrict__ GT,          // [256][2048]
                                             float* __restrict__ el,        // [2048][8]
                                             float* __restrict__ ert,       // [8][2048]
                                             u64* __restrict__ ab) {        // [2048][32]
    const int rt = blockIdx.x, cs = blockIdx.y;
    const int t = threadIdx.x;
    if (cs >= 8) {                            // adj bitmask path
        const int b = (cs - 8) * 128 + rt;    // 0..255, 8 rows each
        const int r0 = b * 8;
        const int lane = t & 63;
#pragma unroll 4
        for (int k = 0; k < 64; ++k) {
            int tl = k * 256 + t;
            int W = tl >> 6;
            int rl = W >> 5, jw = W & 31;
            int a = adj[(size_t)(r0 + rl) * NN + jw * 64 + lane];
            u64 mk = __ballot(a != 0);
            if (lane == 0) ab[(size_t)(r0 + rl) * 32 + jw] = mk;
        }
        return;
    }
    const int i0 = rt * 16;
    const int lane = t & 63, w = t >> 6;
    const int q = lane >> 4, n = lane & 15;
    const int ct = w & 1, kh = w >> 1;
    __shared__ __align__(16) u16 As[16][520];   // pad: 520*2B stride -> 2-way banks (free)
    __shared__ __align__(16) u16 Bs[32][520];
    __shared__ float osh[2][16][16];
    __shared__ float pel[2][16], per_[2][16];

    // stage A: rows i0..i0+15 of x (8192 contiguous f32), coalesced float4 + cvt_pk
    {
        const float4* xs = (const float4*)(x + (size_t)i0 * 512);
#pragma unroll
        for (int j = 0; j < 8; ++j) {
            float4 v = xs[j * 256 + t];
            int off = (j * 256 + t) * 4;      // float index in 16x512 tile
            int r = off >> 9, k = off & 511;
            uint2 o;
            o.x = pk2(v.x, v.y);
            o.y = pk2(v.z, v.w);
            *(uint2*)&As[r][k] = o;
        }
    }
    // stage B^T: cols cs*32..+31 of W1 (coalesced 128B per 32-lane group)
    {
        const int cl = t & 31, kr0 = t >> 5;
#pragma unroll 4
        for (int it = 0; it < 64; ++it) {
            int k = it * 8 + kr0;
            Bs[cl][k] = (u16)bfb(W1[(size_t)k * 256 + cs * 32 + cl]);
        }
    }
    __syncthreads();

    const u16* apl = &As[n][kh * 256 + q * 8];
    const u16* bpl = &Bs[ct * 16 + n][kh * 256 + q * 8];
    f32x4 acc = {0.f, 0.f, 0.f, 0.f};
#pragma unroll
    for (int ks = 0; ks < 8; ++ks) {
        short8 a = *(const short8*)(apl + ks * 32);
        short8 b = *(const short8*)(bpl + ks * 32);
        acc = __builtin_amdgcn_mfma_f32_16x16x32_bf16(a, b, acc, 0, 0, 0);
    }
    __syncthreads();
    if (kh == 1) {
#pragma unroll
        for (int r = 0; r < 4; ++r) osh[ct][q * 4 + r][n] = acc[r];
    }
    __syncthreads();
    if (kh == 0) {
#pragma unroll
        for (int r = 0; r < 4; ++r) acc[r] += osh[ct][q * 4 + r][n];
        uint2 g0;
        g0.x = pk2(acc[0], acc[1]);
        g0.y = pk2(acc[2], acc[3]);
        *(uint2*)&GT[(size_t)(cs * 32 + ct * 16 + n) * NN + i0 + q * 4] = g0;
        const float alv = al[ct * 16 + n], arv = ar[ct * 16 + n];
#pragma unroll
        for (int r = 0; r < 4; ++r) {
            float ve = acc[r] * alv, vr = acc[r] * arv;
#pragma unroll
            for (int off = 1; off <= 8; off <<= 1) {
                ve += __shfl_xor(ve, off);
                vr += __shfl_xor(vr, off);
            }
            if (n == 0) { pel[ct][q * 4 + r] = ve; per_[ct][q * 4 + r] = vr; }
        }
    }
    __syncthreads();
    if (t < 16) {
        el[(size_t)(i0 + t) * 8 + cs] = pel[0][t] + pel[1][t];
        ert[(size_t)cs * NN + i0 + t] = per_[0][t] + per_[1][t];
    }
}

// ---------------- gemm2 (+ fused W2 conversion): 16 rows x 32 cols, K=256 from LDS ----------------
__global__ __launch_bounds__(256) void gemm2(const u16* __restrict__ A,    // hbb [2048][256] bf16
                                             const float* __restrict__ W2, // [256][128]
                                             const float* __restrict__ al,
                                             const float* __restrict__ ar,
                                             u16* __restrict__ GT,         // [128][2048]
                                             float* __restrict__ el2p,     // [4][2048]
                                             float* __restrict__ er2p) {   // [4][2048]
    const int i0 = blockIdx.x * 16, cs = blockIdx.y;
    const int t = threadIdx.x, lane = t & 63, w = t >> 6;
    const int q = lane >> 4, n = lane & 15;
    const int ct = w & 1, kh = w >> 1;
    __shared__ __align__(16) u16 As[16][264];
    __shared__ __align__(16) u16 Bs[32][264];
    __shared__ float osh[2][16][16];
    __shared__ float pel[2][16], per_[2][16];

    // stage A: rows i0..i0+15 of hbb (4096 contiguous u16), coalesced uint2
    {
        const uint2* hs = (const uint2*)(A + (size_t)i0 * 256);
#pragma unroll
        for (int j = 0; j < 4; ++j) {
            uint2 v = hs[j * 256 + t];
            int off = (j * 256 + t) * 4;      // u16 index in 16x256 tile
            int r = off >> 8, k = off & 255;
            *(uint2*)&As[r][k] = v;
        }
    }
    // stage B^T: cols cs*32..+31 of W2
    {
        const int cl = t & 31, kr0 = t >> 5;
#pragma unroll 4
        for (int it = 0; it < 32; ++it) {
            int k = it * 8 + kr0;
            Bs[cl][k] = (u16)bfb(W2[(size_t)k * 128 + cs * 32 + cl]);
        }
    }
    __syncthreads();

    const u16* apl = &As[n][kh * 128 + q * 8];
    const u16* bpl = &Bs[ct * 16 + n][kh * 128 + q * 8];
    f32x4 acc = {0.f, 0.f, 0.f, 0.f};
#pragma unroll
    for (int ks = 0; ks < 4; ++ks) {
        short8 a = *(const short8*)(apl + ks * 32);
        short8 b = *(const short8*)(bpl + ks * 32);
        acc = __builtin_amdgcn_mfma_f32_16x16x32_bf16(a, b, acc, 0, 0, 0);
    }
    __syncthreads();
    if (kh == 1) {
#pragma unroll
        for (int r = 0; r < 4; ++r) osh[ct][q * 4 + r][n] = acc[r];
    }
    __syncthreads();
    if (kh == 0) {
#pragma unroll
        for (int r = 0; r < 4; ++r) acc[r] += osh[ct][q * 4 + r][n];
        uint2 g0;
        g0.x = pk2(acc[0], acc[1]);
        g0.y = pk2(acc[2], acc[3]);
        *(uint2*)&GT[(size_t)(cs * 32 + ct * 16 + n) * NN + i0 + q * 4] = g0;
        const float alv = al[cs * 32 + ct * 16 + n], arv = ar[cs * 32 + ct * 16 + n];
#pragma unroll
        for (int r = 0; r < 4; ++r) {
            float ve = acc[r] * alv, vr = acc[r] * arv;
#pragma unroll
            for (int off = 1; off <= 8; off <<= 1) {
                ve += __shfl_xor(ve, off);
                vr += __shfl_xor(vr, off);
            }
            if (n == 0) { pel[ct][q * 4 + r] = ve; per_[ct][q * 4 + r] = vr; }
        }
    }
    __syncthreads();
    if (t < 16) {
        el2p[(size_t)cs * NN + i0 + t] = pel[0][t] + pel[1][t];
        er2p[(size_t)cs * NN + i0 + t] = per_[0][t] + per_[1][t];
    }
}

// ---------------- attn1: 16 rows x 2 heads (64 cols), 256-j tiles (8 phases), dbuf pl ----------------
__global__ __launch_bounds__(512, 4) void attn1(const float* __restrict__ el,      // [2048][8]
                                                const float* __restrict__ ert,     // [8][2048]
                                                const unsigned* __restrict__ ab32, // [2048][64]
                                                const u16* __restrict__ gbt,       // [256][2048]
                                                u16* __restrict__ hbb) {           // [2048][256]
    const int rt = blockIdx.x, sec = blockIdx.y;
    const int i0 = rt * 16, h0 = sec * 2;
    const int t = threadIdx.x, lane = t & 63, w = t >> 6;
    const int q = lane >> 4, n = lane & 15;
    const int m = t >> 5, jq = t & 31;
    const int hl = w >> 2, ch = (w >> 1) & 1, kf2 = w & 1;

    __shared__ u16 ersb[2][2048];                     // bf16 er
    __shared__ __align__(16) u16 pl[2][2][16][264];   // [buf][h][m][k]
    __shared__ unsigned absh[16][64];
    __shared__ float psum_sh[16][2];
    __shared__ float osh[2][2][16][16];
    __shared__ float wmax[2][8];
    __shared__ float mxsh[2];

    float4 v0 = *(const float4*)(ert + (size_t)h0 * NN + t * 4);
    float4 v1 = *(const float4*)(ert + (size_t)(h0 + 1) * NN + t * 4);
    uint2 c0, c1;
    c0.x = pk2(v0.x, v0.y); c0.y = pk2(v0.z, v0.w);
    c1.x = pk2(v1.x, v1.y); c1.y = pk2(v1.z, v1.w);
    *(uint2*)&ersb[0][t * 4] = c0;
    *(uint2*)&ersb[1][t * 4] = c1;
    float m0 = fmaxf(fmaxf(v0.x, v0.y), fmaxf(v0.z, v0.w));
    float m1 = fmaxf(fmaxf(v1.x, v1.y), fmaxf(v1.z, v1.w));
#pragma unroll
    for (int off = 32; off; off >>= 1) {
        m0 = fmaxf(m0, __shfl_xor(m0, off));
        m1 = fmaxf(m1, __shfl_xor(m1, off));
    }
    if (lane == 0) { wmax[0][w] = m0; wmax[1][w] = m1; }
    for (int c = t; c < 1024; c += 512)
        absh[c >> 6][c & 63] = ab32[(size_t)(i0 + (c >> 6)) * 64 + (c & 63)];
    __syncthreads();
    if (t < 2) {
        float mm = wmax[t][0];
#pragma unroll
        for (int ww = 1; ww < 8; ++ww) mm = fmaxf(mm, wmax[t][ww]);
        mxsh[t] = mm;
    }
    __syncthreads();

    float elv[2], mxv[2], ps[2];
#pragma unroll
    for (int h = 0; h < 2; ++h) {
        float e = el[(size_t)(i0 + m) * 8 + h0 + h];
        elv[h] = e;
        float mm = e + mxsh[h];
        mxv[h] = fmaxf(mm, 0.2f * mm);
        ps[h] = 0.f;
    }

    auto stage = [&](int tl, int nb) {
#pragma unroll
        for (int sub = 0; sub < 2; ++sub) {
            unsigned word = absh[m][tl * 8 + sub * 4 + (jq >> 3)];
            unsigned bits = (word >> ((jq & 7) * 4)) & 0xFu;
            const int jo = tl * 256 + sub * 128 + jq * 4;
            uint2 raw0 = *(const uint2*)&ersb[0][jo];
            uint2 raw1 = *(const uint2*)&ersb[1][jo];
#pragma unroll
            for (int h = 0; h < 2; ++h) {
                uint2 raw = h ? raw1 : raw0;
                float e0 = __uint_as_float(raw.x << 16);
                float e1 = __uint_as_float(raw.x & 0xFFFF0000u);
                float e2 = __uint_as_float(raw.y << 16);
                float e3 = __uint_as_float(raw.y & 0xFFFF0000u);
                float s0 = elv[h] + e0, s1 = elv[h] + e1, s2 = elv[h] + e2, s3 = elv[h] + e3;
                s0 = fmaxf(s0, 0.2f * s0) - mxv[h];
                s1 = fmaxf(s1, 0.2f * s1) - mxv[h];
                s2 = fmaxf(s2, 0.2f * s2) - mxv[h];
                s3 = fmaxf(s3, 0.2f * s3) - mxv[h];
                float p0 = (bits & 1u) ? __expf(s0) : 0.f;
                float p1 = (bits & 2u) ? __expf(s1) : 0.f;
                float p2 = (bits & 4u) ? __expf(s2) : 0.f;
                float p3 = (bits & 8u) ? __expf(s3) : 0.f;
                ps[h] += (p0 + p1) + (p2 + p3);
                uint2 pkv;
                pkv.x = pk2(p0, p1);
                pkv.y = pk2(p2, p3);
                *(uint2*)&pl[nb][h][m][sub * 128 + jq * 4] = pkv;
            }
        }
    };

    const int col = sec * 64 + hl * 32 + ch * 16 + n;
    const u16* gb = gbt + (size_t)col * NN + kf2 * 128 + q * 8;
    short8 bc0 = *(const short8*)gb;
    short8 bc1 = *(const short8*)(gb + 32);
    short8 bc2 = *(const short8*)(gb + 64);
    short8 bc3 = *(const short8*)(gb + 96);
    f32x4 acc = {0.f, 0.f, 0.f, 0.f};

    stage(0, 0);
    __syncthreads();

    for (int tile = 0; tile < 8; ++tile) {
        short8 bn0 = bc0, bn1 = bc1, bn2 = bc2, bn3 = bc3;
        if (tile < 7) {
            const u16* gq = gb + (tile + 1) * 256;
            bn0 = *(const short8*)gq;
            bn1 = *(const short8*)(gq + 32);
            bn2 = *(const short8*)(gq + 64);
            bn3 = *(const short8*)(gq + 96);
        }
        const u16* ap = &pl[tile & 1][hl][n][kf2 * 128 + q * 8];
        short8 a0 = *(const short8*)ap;
        short8 a1 = *(const short8*)(ap + 32);
        short8 a2 = *(const short8*)(ap + 64);
        short8 a3 = *(const short8*)(ap + 96);
        acc = __builtin_amdgcn_mfma_f32_16x16x32_bf16(a0, bc0, acc, 0, 0, 0);
        acc = __builtin_amdgcn_mfma_f32_16x16x32_bf16(a1, bc1, acc, 0, 0, 0);
        acc = __builtin_amdgcn_mfma_f32_16x16x32_bf16(a2, bc2, acc, 0, 0, 0);
        acc = __builtin_amdgcn_mfma_f32_16x16x32_bf16(a3, bc3, acc, 0, 0, 0);
        if (tile < 7) stage(tile + 1, (tile + 1) & 1);
        bc0 = bn0; bc1 = bn1; bc2 = bn2; bc3 = bn3;
        __syncthreads();
    }

#pragma unroll
    for (int h = 0; h < 2; ++h) {
        float v = ps[h];
#pragma unroll
        for (int off = 16; off; off >>= 1) v += __shfl_down(v, off, 32);
        if (jq == 0) psum_sh[m][h] = v;
    }
    if (kf2 == 1) {
#pragma unroll
        for (int r = 0; r < 4; ++r) osh[hl][ch][q * 4 + r][n] = acc[r];
    }
    __syncthreads();
    if (kf2 == 0) {
#pragma unroll
        for (int r = 0; r < 4; ++r) {
            int mr = q * 4 + r;
            float o = (acc[r] + osh[hl][ch][mr][n]) / psum_sh[mr][hl];
            o = o > 0.f ? o : (__expf(o) - 1.f); // ELU
            hbb[(size_t)(i0 + mr) * 256 + col] = (u16)bfb(o);
        }
    }
}

// ---------------- attn2: 16 rows x 64 cols (1 head), 256-j tiles (8 phases), dbuf ----------------
__global__ __launch_bounds__(512) void attn2(const float* __restrict__ el2p,    // [4][2048]
                                             const float* __restrict__ er2p,    // [4][2048]
                                             const unsigned* __restrict__ ab32,
                                             const u16* __restrict__ gbt,       // [128][2048]
                                             float* __restrict__ out) {         // [2048][128]
    const int rt = blockIdx.x, sec = blockIdx.y;
    const int i0 = rt * 16;
    const int t = threadIdx.x, lane = t & 63, w = t >> 6;
    const int q = lane >> 4, n = lane & 15;
    const int m = t >> 5, jq = t & 31;
    const int ct = w >> 1, kf2 = w & 1;

    __shared__ u16 ersb[2048];
    __shared__ __align__(16) u16 pl[2][16][264];
    __shared__ unsigned absh[16][64];
    __shared__ float psum_sh[16];
    __shared__ float osh[4][16][16];
    __shared__ float wmax[8];
    __shared__ float mxsh;

    float4 a0 = *(const float4*)(er2p + t * 4);
    float4 a1 = *(const float4*)(er2p + NN + t * 4);
    float4 a2 = *(const float4*)(er2p + 2 * NN + t * 4);
    float4 a3 = *(const float4*)(er2p + 3 * NN + t * 4);
    float4 v0;
    v0.x = ((a0.x + a1.x) + (a2.x + a3.x));
    v0.y = ((a0.y + a1.y) + (a2.y + a3.y));
    v0.z = ((a0.z + a1.z) + (a2.z + a3.z));
    v0.w = ((a0.w + a1.w) + (a2.w + a3.w));
    uint2 c0;
    c0.x = pk2(v0.x, v0.y); c0.y = pk2(v0.z, v0.w);
    *(uint2*)&ersb[t * 4] = c0;
    float m0 = fmaxf(fmaxf(v0.x, v0.y), fmaxf(v0.z, v0.w));
#pragma unroll
    for (int off = 32; off; off >>= 1) m0 = fmaxf(m0, __shfl_xor(m0, off));
    if (lane == 0) wmax[w] = m0;
    for (int c = t; c < 1024; c += 512)
        absh[c >> 6][c & 63] = ab32[(size_t)(i0 + (c >> 6)) * 64 + (c & 63)];
    __syncthreads();
    if (t == 0) {
        float mm = wmax[0];
#pragma unroll
        for (int ww = 1; ww < 8; ++ww) mm = fmaxf(mm, wmax[ww]);
        mxsh = mm;
    }
    __syncthreads();

    const float elv = el2p[i0 + m] + el2p[NN + i0 + m] + el2p[2 * NN + i0 + m] + el2p[3 * NN + i0 + m];
    float mm2 = elv + mxsh;
    const float mxv = fmaxf(mm2, 0.2f * mm2);
    float ps = 0.f;

    auto stage = [&](int tl, int nb) {
#pragma unroll
        for (int sub = 0; sub < 2; ++sub) {
            unsigned word = absh[m][tl * 8 + sub * 4 + (jq >> 3)];
            unsigned bits = (word >> ((jq & 7) * 4)) & 0xFu;
            const int jo = tl * 256 + sub * 128 + jq * 4;
            uint2 raw = *(const uint2*)&ersb[jo];
            float e0 = __uint_as_float(raw.x << 16);
            float e1 = __uint_as_float(raw.x & 0xFFFF0000u);
            float e2 = __uint_as_float(raw.y << 16);
            float e3 = __uint_as_float(raw.y & 0xFFFF0000u);
            float s0 = elv + e0, s1 = elv + e1, s2 = elv + e2, s3 = elv + e3;
            s0 = fmaxf(s0, 0.2f * s0) - mxv;
            s1 = fmaxf(s1, 0.2f * s1) - mxv;
            s2 = fmaxf(s2, 0.2f * s2) - mxv;
            s3 = fmaxf(s3, 0.2f * s3) - mxv;
            float p0 = (bits & 1u) ? __expf(s0) : 0.f;
            float p1 = (bits & 2u) ? __expf(s1) : 0.f;
            float p2 = (bits & 4u) ? __expf(s2) : 0.f;
            float p3 = (bits & 8u) ? __expf(s3) : 0.f;
            ps += (p0 + p1) + (p2 + p3);
            uint2 pkv;
            pkv.x = pk2(p0, p1);
            pkv.y = pk2(p2, p3);
            *(uint2*)&pl[nb][m][sub * 128 + jq * 4] = pkv;
        }
    };

    const int col = sec * 64 + ct * 16 + n;
    const u16* gb = gbt + (size_t)col * NN + kf2 * 128 + q * 8;
    short8 bc0 = *(const short8*)gb;
    short8 bc1 = *(const short8*)(gb + 32);
    short8 bc2 = *(const short8*)(gb + 64);
    short8 bc3 = *(const short8*)(gb + 96);
    f32x4 acc = {0.f, 0.f, 0.f, 0.f};

    stage(0, 0);
    __syncthreads();

    for (int tile = 0; tile < 8; ++tile) {
        short8 bn0 = bc0, bn1 = bc1, bn2 = bc2, bn3 = bc3;
        if (tile < 7) {
            const u16* gq = gb + (tile + 1) * 256;
            bn0 = *(const short8*)gq;
            bn1 = *(const short8*)(gq + 32);
            bn2 = *(const short8*)(gq + 64);
            bn3 = *(const short8*)(gq + 96);
        }
        const u16* ap = &pl[tile & 1][n][kf2 * 128 + q * 8];
        short8 a0v = *(const short8*)ap;
        short8 a1v = *(const short8*)(ap + 32);
        short8 a2v = *(const short8*)(ap + 64);
        short8 a3v = *(const short8*)(ap + 96);
        acc = __builtin_amdgcn_mfma_f32_16x16x32_bf16(a0v, bc0, acc, 0, 0, 0);
        acc = __builtin_amdgcn_mfma_f32_16x16x32_bf16(a1v, bc1, acc, 0, 0, 0);
        acc = __builtin_amdgcn_mfma_f32_16x16x32_bf16(a2v, bc2, acc, 0, 0, 0);
        acc = __builtin_amdgcn_mfma_f32_16x16x32_bf16(a3v, bc3, acc, 0, 0, 0);
        if (tile < 7) stage(tile + 1, (tile + 1) & 1);
        bc0 = bn0; bc1 = bn1; bc2 = bn2; bc3 = bn3;
        __syncthreads();
    }

#pragma unroll
    for (int off = 16; off; off >>= 1) ps += __shfl_down(ps, off, 32);
    if (jq == 0) psum_sh[m] = ps;
    if (kf2 == 1) {
#pragma unroll
        for (int r = 0; r < 4; ++r) osh[ct][q * 4 + r][n] = acc[r];
    }
    __syncthreads();
    if (kf2 == 0) {
#pragma unroll
        for (int r = 0; r < 4; ++r) {
            int mr = q * 4 + r;
            out[(size_t)(i0 + mr) * 128 + col] = (acc[r] + osh[ct][mr][n]) / psum_sh[mr];
        }
    }
}

extern "C" void kernel_launch(void* const* d_in, const int* in_sizes, int n_in,
                              void* d_out, int out_size, void* d_ws, size_t ws_size,
                              hipStream_t stream) {
    const float* x   = (const float*)d_in[0];
    const float* W1  = (const float*)d_in[1];
    const float* a1l = (const float*)d_in[2];
    const float* a1r = (const float*)d_in[3];
    const float* W2  = (const float*)d_in[4];
    const float* a2l = (const float*)d_in[5];
    const float* a2r = (const float*)d_in[6];
    const int* adj = (const int*)d_in[7];

    char* p = (char*)d_ws;
    unsigned* abits = (unsigned*)p;  p += (size_t)NN * 64 * 4;
    u16* gbt1  = (u16*)p;            p += (size_t)256 * NN * 2;
    u16* hbb   = (u16*)p;            p += (size_t)NN * 256 * 2;
    u16* gbt2  = (u16*)p;            p += (size_t)128 * NN * 2;
    float* el1 = (float*)p;          p += (size_t)NN * 8 * 4;
    float* ert1 = (float*)p;         p += (size_t)8 * NN * 4;
    float* el2p = (float*)p;         p += (size_t)4 * NN * 4;
    float* er2p = (float*)p;         p += (size_t)4 * NN * 4;

    gemm1<<<dim3(128, 10), 256, 0, stream>>>(x, W1, adj, a1l, a1r, gbt1, el1, ert1, (u64*)abits);
    attn1<<<dim3(128, 4), 512, 0, stream>>>(el1, ert1, abits, gbt1, hbb);

    gemm2<<<dim3(128, 4), 256, 0, stream>>>(hbb, W2, a2l, a2r, gbt2, el2p, er2p);
    attn2<<<dim3(128, 2), 512, 0, stream>>>(el2p, er2p, abits, gbt2, (float*)d_out);
}

// Round 3
// 123.800 us; speedup vs baseline: 1.1245x; 1.1245x over previous
//
#include <hip/hip_runtime.h>
#include <hip/hip_bf16.h>

#define NN 2048
typedef unsigned short u16;
typedef unsigned long long u64;
typedef __attribute__((ext_vector_type(8))) short short8;
typedef __attribute__((ext_vector_type(4))) float f32x4;

// fp32 -> bf16 bits, RNE (scalar path)
__device__ __forceinline__ unsigned bfb(float x) {
    unsigned u = __float_as_uint(x);
    return (u + 0x7FFFu + ((u >> 16) & 1u)) >> 16;
}
// packed pair via HW cvt (identical RNE bits, 1 instr)
__device__ __forceinline__ unsigned pk2(float a, float b) {
    unsigned r;
    asm("v_cvt_pk_bf16_f32 %0, %1, %2" : "=v"(r) : "v"(a), "v"(b));
    return r;
}

// ---------------- gemm1: 16x32 tile, K=512 LDS-staged (fused x/W1 conversion),
// adj bitmask distributed across ALL 1024 blocks (16 independent loads/thread,
// ballots deferred past staging so HBM latency overlaps LDS work). ----------------
__global__ __launch_bounds__(256) void gemm1(const float* __restrict__ x,   // [2048][512]
                                             const float* __restrict__ W1,  // [512][256]
                                             const int* __restrict__ adj,   // [2048][2048]
                                             const float* __restrict__ al,
                                             const float* __restrict__ ar,
                                             u16* __restrict__ GT,          // [256][2048]
                                             float* __restrict__ el,        // [2048][8]
                                             float* __restrict__ ert,       // [8][2048]
                                             u64* __restrict__ ab) {        // [2048][32]
    const int rt = blockIdx.x, cs = blockIdx.y;
    const int i0 = rt * 16;
    const int t = threadIdx.x, lane = t & 63, w = t >> 6;
    const int q = lane >> 4, n = lane & 15;
    const int ct = w & 1, kh = w >> 1;
    __shared__ __align__(16) u16 As[16][520];
    __shared__ __align__(16) u16 Bs[32][520];
    __shared__ float osh[2][16][16];
    __shared__ float pel[2][16], per_[2][16];

    // adj bitmask: 64 ballot-units per block; issue all 16 loads up front
    const int b = cs * 128 + rt;          // 0..1023
    const int u0 = b * 64 + w * 16;
    int av[16];
#pragma unroll
    for (int it = 0; it < 16; ++it) {
        int u = u0 + it;
        av[it] = adj[(size_t)(u >> 5) * NN + (u & 31) * 64 + lane];
    }

    // stage A: rows i0..i0+15 of x, coalesced float4 + cvt_pk; XOR-swizzled cols
    {
        const float4* xs = (const float4*)(x + (size_t)i0 * 512);
#pragma unroll
        for (int j = 0; j < 8; ++j) {
            float4 v = xs[j * 256 + t];
            int off = (j * 256 + t) * 4;
            int r = off >> 9, k = off & 511;
            uint2 o;
            o.x = pk2(v.x, v.y);
            o.y = pk2(v.z, v.w);
            *(uint2*)&As[r][k ^ ((r & 7) << 3)] = o;   // r uniform per wave: conflict-free
        }
    }
    // stage B^T: cols cs*32..+31 of W1, float4 row-chunks (16 passes, pipelined)
    {
        const int c4 = (t & 7) * 4, kq = t >> 3;       // 8 col-quads x 32 k per pass
#pragma unroll 8
        for (int pass = 0; pass < 16; ++pass) {
            int k = pass * 32 + kq;
            float4 v = *(const float4*)(W1 + (size_t)k * 256 + cs * 32 + c4);
            Bs[c4 + 0][k ^ (((c4 + 0) & 7) << 3)] = (u16)bfb(v.x);
            Bs[c4 + 1][k ^ (((c4 + 1) & 7) << 3)] = (u16)bfb(v.y);
            Bs[c4 + 2][k ^ (((c4 + 2) & 7) << 3)] = (u16)bfb(v.z);
            Bs[c4 + 3][k ^ (((c4 + 3) & 7) << 3)] = (u16)bfb(v.w);
        }
    }
    // ballots: consume adj loads (their latency was hidden under staging)
#pragma unroll
    for (int it = 0; it < 16; ++it) {
        u64 mk = __ballot(av[it] != 0);
        int u = u0 + it;
        if (lane == 0) ab[(size_t)(u >> 5) * 32 + (u & 31)] = mk;
    }
    __syncthreads();

    const int an = n, bn = ct * 16 + n;
    const int k0 = kh * 256 + q * 8;
    f32x4 acc = {0.f, 0.f, 0.f, 0.f};
#pragma unroll
    for (int ks = 0; ks < 8; ++ks) {
        short8 a = *(const short8*)&As[an][(k0 + ks * 32) ^ ((an & 7) << 3)];
        short8 bb = *(const short8*)&Bs[bn][(k0 + ks * 32) ^ ((bn & 7) << 3)];
        acc = __builtin_amdgcn_mfma_f32_16x16x32_bf16(a, bb, acc, 0, 0, 0);
    }
    if (kh == 1) {
#pragma unroll
        for (int r = 0; r < 4; ++r) osh[ct][q * 4 + r][n] = acc[r];
    }
    __syncthreads();
    if (kh == 0) {
#pragma unroll
        for (int r = 0; r < 4; ++r) acc[r] += osh[ct][q * 4 + r][n];
        uint2 g0;
        g0.x = pk2(acc[0], acc[1]);
        g0.y = pk2(acc[2], acc[3]);
        *(uint2*)&GT[(size_t)(cs * 32 + ct * 16 + n) * NN + i0 + q * 4] = g0;
        const float alv = al[ct * 16 + n], arv = ar[ct * 16 + n];
#pragma unroll
        for (int r = 0; r < 4; ++r) {
            float ve = acc[r] * alv, vr = acc[r] * arv;
#pragma unroll
            for (int off = 1; off <= 8; off <<= 1) {
                ve += __shfl_xor(ve, off);
                vr += __shfl_xor(vr, off);
            }
            if (n == 0) { pel[ct][q * 4 + r] = ve; per_[ct][q * 4 + r] = vr; }
        }
    }
    __syncthreads();
    if (t < 16) {
        el[(size_t)(i0 + t) * 8 + cs] = pel[0][t] + pel[1][t];
        ert[(size_t)cs * NN + i0 + t] = per_[0][t] + per_[1][t];
    }
}

// ---------------- gemm2 (+ fused W2 conversion): 16x32 tile, K=256 LDS-staged, swizzled ----------------
__global__ __launch_bounds__(256) void gemm2(const u16* __restrict__ A,    // hbb [2048][256] bf16
                                             const float* __restrict__ W2, // [256][128]
                                             const float* __restrict__ al,
                                             const float* __restrict__ ar,
                                             u16* __restrict__ GT,         // [128][2048]
                                             float* __restrict__ el2p,     // [4][2048]
                                             float* __restrict__ er2p) {   // [4][2048]
    const int i0 = blockIdx.x * 16, cs = blockIdx.y;
    const int t = threadIdx.x, lane = t & 63, w = t >> 6;
    const int q = lane >> 4, n = lane & 15;
    const int ct = w & 1, kh = w >> 1;
    __shared__ __align__(16) u16 As[16][264];
    __shared__ __align__(16) u16 Bs[32][264];
    __shared__ float osh[2][16][16];
    __shared__ float pel[2][16], per_[2][16];

    // stage A: rows i0..i0+15 of hbb, coalesced uint2; swizzled
    {
        const uint2* hs = (const uint2*)(A + (size_t)i0 * 256);
#pragma unroll
        for (int j = 0; j < 4; ++j) {
            uint2 v = hs[j * 256 + t];
            int off = (j * 256 + t) * 4;
            int r = off >> 8, k = off & 255;
            *(uint2*)&As[r][k ^ ((r & 7) << 3)] = v;   // r uniform per wave
        }
    }
    // stage B^T: cols cs*32..+31 of W2, float4 row-chunks (8 passes)
    {
        const int c4 = (t & 7) * 4, kq = t >> 3;
#pragma unroll 8
        for (int pass = 0; pass < 8; ++pass) {
            int k = pass * 32 + kq;
            float4 v = *(const float4*)(W2 + (size_t)k * 128 + cs * 32 + c4);
            Bs[c4 + 0][k ^ (((c4 + 0) & 7) << 3)] = (u16)bfb(v.x);
            Bs[c4 + 1][k ^ (((c4 + 1) & 7) << 3)] = (u16)bfb(v.y);
            Bs[c4 + 2][k ^ (((c4 + 2) & 7) << 3)] = (u16)bfb(v.z);
            Bs[c4 + 3][k ^ (((c4 + 3) & 7) << 3)] = (u16)bfb(v.w);
        }
    }
    __syncthreads();

    const int an = n, bn = ct * 16 + n;
    const int k0 = kh * 128 + q * 8;
    f32x4 acc = {0.f, 0.f, 0.f, 0.f};
#pragma unroll
    for (int ks = 0; ks < 4; ++ks) {
        short8 a = *(const short8*)&As[an][(k0 + ks * 32) ^ ((an & 7) << 3)];
        short8 bb = *(const short8*)&Bs[bn][(k0 + ks * 32) ^ ((bn & 7) << 3)];
        acc = __builtin_amdgcn_mfma_f32_16x16x32_bf16(a, bb, acc, 0, 0, 0);
    }
    if (kh == 1) {
#pragma unroll
        for (int r = 0; r < 4; ++r) osh[ct][q * 4 + r][n] = acc[r];
    }
    __syncthreads();
    if (kh == 0) {
#pragma unroll
        for (int r = 0; r < 4; ++r) acc[r] += osh[ct][q * 4 + r][n];
        uint2 g0;
        g0.x = pk2(acc[0], acc[1]);
        g0.y = pk2(acc[2], acc[3]);
        *(uint2*)&GT[(size_t)(cs * 32 + ct * 16 + n) * NN + i0 + q * 4] = g0;
        const float alv = al[cs * 32 + ct * 16 + n], arv = ar[cs * 32 + ct * 16 + n];
#pragma unroll
        for (int r = 0; r < 4; ++r) {
            float ve = acc[r] * alv, vr = acc[r] * arv;
#pragma unroll
            for (int off = 1; off <= 8; off <<= 1) {
                ve += __shfl_xor(ve, off);
                vr += __shfl_xor(vr, off);
            }
            if (n == 0) { pel[ct][q * 4 + r] = ve; per_[ct][q * 4 + r] = vr; }
        }
    }
    __syncthreads();
    if (t < 16) {
        el2p[(size_t)cs * NN + i0 + t] = pel[0][t] + pel[1][t];
        er2p[(size_t)cs * NN + i0 + t] = per_[0][t] + per_[1][t];
    }
}

// ---------------- attn1: 16 rows x 2 heads (64 cols), 256-j tiles (8 phases), dbuf pl ----------------
__global__ __launch_bounds__(512, 4) void attn1(const float* __restrict__ el,      // [2048][8]
                                                const float* __restrict__ ert,     // [8][2048]
                                                const unsigned* __restrict__ ab32, // [2048][64]
                                                const u16* __restrict__ gbt,       // [256][2048]
                                                u16* __restrict__ hbb) {           // [2048][256]
    const int rt = blockIdx.x, sec = blockIdx.y;
    const int i0 = rt * 16, h0 = sec * 2;
    const int t = threadIdx.x, lane = t & 63, w = t >> 6;
    const int q = lane >> 4, n = lane & 15;
    const int m = t >> 5, jq = t & 31;
    const int hl = w >> 2, ch = (w >> 1) & 1, kf2 = w & 1;

    __shared__ u16 ersb[2][2048];                     // bf16 er
    __shared__ __align__(16) u16 pl[2][2][16][264];   // [buf][h][m][k]
    __shared__ unsigned absh[16][64];
    __shared__ float psum_sh[16][2];
    __shared__ float osh[2][2][16][16];
    __shared__ float wmax[2][8];
    __shared__ float mxsh[2];

    float4 v0 = *(const float4*)(ert + (size_t)h0 * NN + t * 4);
    float4 v1 = *(const float4*)(ert + (size_t)(h0 + 1) * NN + t * 4);
    uint2 c0, c1;
    c0.x = pk2(v0.x, v0.y); c0.y = pk2(v0.z, v0.w);
    c1.x = pk2(v1.x, v1.y); c1.y = pk2(v1.z, v1.w);
    *(uint2*)&ersb[0][t * 4] = c0;
    *(uint2*)&ersb[1][t * 4] = c1;
    float m0 = fmaxf(fmaxf(v0.x, v0.y), fmaxf(v0.z, v0.w));
    float m1 = fmaxf(fmaxf(v1.x, v1.y), fmaxf(v1.z, v1.w));
#pragma unroll
    for (int off = 32; off; off >>= 1) {
        m0 = fmaxf(m0, __shfl_xor(m0, off));
        m1 = fmaxf(m1, __shfl_xor(m1, off));
    }
    if (lane == 0) { wmax[0][w] = m0; wmax[1][w] = m1; }
    for (int c = t; c < 1024; c += 512)
        absh[c >> 6][c & 63] = ab32[(size_t)(i0 + (c >> 6)) * 64 + (c & 63)];
    __syncthreads();
    if (t < 2) {
        float mm = wmax[t][0];
#pragma unroll
        for (int ww = 1; ww < 8; ++ww) mm = fmaxf(mm, wmax[t][ww]);
        mxsh[t] = mm;
    }
    __syncthreads();

    float elv[2], mxv[2], ps[2];
#pragma unroll
    for (int h = 0; h < 2; ++h) {
        float e = el[(size_t)(i0 + m) * 8 + h0 + h];
        elv[h] = e;
        float mm = e + mxsh[h];
        mxv[h] = fmaxf(mm, 0.2f * mm);
        ps[h] = 0.f;
    }

    auto stage = [&](int tl, int nb) {
#pragma unroll
        for (int sub = 0; sub < 2; ++sub) {
            unsigned word = absh[m][tl * 8 + sub * 4 + (jq >> 3)];
            unsigned bits = (word >> ((jq & 7) * 4)) & 0xFu;
            const int jo = tl * 256 + sub * 128 + jq * 4;
            uint2 raw0 = *(const uint2*)&ersb[0][jo];
            uint2 raw1 = *(const uint2*)&ersb[1][jo];
#pragma unroll
            for (int h = 0; h < 2; ++h) {
                uint2 raw = h ? raw1 : raw0;
                float e0 = __uint_as_float(raw.x << 16);
                float e1 = __uint_as_float(raw.x & 0xFFFF0000u);
                float e2 = __uint_as_float(raw.y << 16);
                float e3 = __uint_as_float(raw.y & 0xFFFF0000u);
                float s0 = elv[h] + e0, s1 = elv[h] + e1, s2 = elv[h] + e2, s3 = elv[h] + e3;
                s0 = fmaxf(s0, 0.2f * s0) - mxv[h];
                s1 = fmaxf(s1, 0.2f * s1) - mxv[h];
                s2 = fmaxf(s2, 0.2f * s2) - mxv[h];
                s3 = fmaxf(s3, 0.2f * s3) - mxv[h];
                float p0 = (bits & 1u) ? __expf(s0) : 0.f;
                float p1 = (bits & 2u) ? __expf(s1) : 0.f;
                float p2 = (bits & 4u) ? __expf(s2) : 0.f;
                float p3 = (bits & 8u) ? __expf(s3) : 0.f;
                ps[h] += (p0 + p1) + (p2 + p3);
                uint2 pkv;
                pkv.x = pk2(p0, p1);
                pkv.y = pk2(p2, p3);
                *(uint2*)&pl[nb][h][m][sub * 128 + jq * 4] = pkv;
            }
        }
    };

    const int col = sec * 64 + hl * 32 + ch * 16 + n;
    const u16* gb = gbt + (size_t)col * NN + kf2 * 128 + q * 8;
    short8 bc0 = *(const short8*)gb;
    short8 bc1 = *(const short8*)(gb + 32);
    short8 bc2 = *(const short8*)(gb + 64);
    short8 bc3 = *(const short8*)(gb + 96);
    f32x4 acc = {0.f, 0.f, 0.f, 0.f};

    stage(0, 0);
    __syncthreads();

    for (int tile = 0; tile < 8; ++tile) {
        short8 bn0 = bc0, bn1 = bc1, bn2 = bc2, bn3 = bc3;
        if (tile < 7) {
            const u16* gq = gb + (tile + 1) * 256;
            bn0 = *(const short8*)gq;
            bn1 = *(const short8*)(gq + 32);
            bn2 = *(const short8*)(gq + 64);
            bn3 = *(const short8*)(gq + 96);
        }
        const u16* ap = &pl[tile & 1][hl][n][kf2 * 128 + q * 8];
        short8 a0 = *(const short8*)ap;
        short8 a1 = *(const short8*)(ap + 32);
        short8 a2 = *(const short8*)(ap + 64);
        short8 a3 = *(const short8*)(ap + 96);
        acc = __builtin_amdgcn_mfma_f32_16x16x32_bf16(a0, bc0, acc, 0, 0, 0);
        acc = __builtin_amdgcn_mfma_f32_16x16x32_bf16(a1, bc1, acc, 0, 0, 0);
        acc = __builtin_amdgcn_mfma_f32_16x16x32_bf16(a2, bc2, acc, 0, 0, 0);
        acc = __builtin_amdgcn_mfma_f32_16x16x32_bf16(a3, bc3, acc, 0, 0, 0);
        if (tile < 7) stage(tile + 1, (tile + 1) & 1);
        bc0 = bn0; bc1 = bn1; bc2 = bn2; bc3 = bn3;
        __syncthreads();
    }

#pragma unroll
    for (int h = 0; h < 2; ++h) {
        float v = ps[h];
#pragma unroll
        for (int off = 16; off; off >>= 1) v += __shfl_down(v, off, 32);
        if (jq == 0) psum_sh[m][h] = v;
    }
    if (kf2 == 1) {
#pragma unroll
        for (int r = 0; r < 4; ++r) osh[hl][ch][q * 4 + r][n] = acc[r];
    }
    __syncthreads();
    if (kf2 == 0) {
#pragma unroll
        for (int r = 0; r < 4; ++r) {
            int mr = q * 4 + r;
            float o = (acc[r] + osh[hl][ch][mr][n]) / psum_sh[mr][hl];
            o = o > 0.f ? o : (__expf(o) - 1.f); // ELU
            hbb[(size_t)(i0 + mr) * 256 + col] = (u16)bfb(o);
        }
    }
}

// ---------------- attn2: 16 rows x 64 cols (1 head), 256-j tiles (8 phases), dbuf ----------------
__global__ __launch_bounds__(512) void attn2(const float* __restrict__ el2p,    // [4][2048]
                                             const float* __restrict__ er2p,    // [4][2048]
                                             const unsigned* __restrict__ ab32,
                                             const u16* __restrict__ gbt,       // [128][2048]
                                             float* __restrict__ out) {         // [2048][128]
    const int rt = blockIdx.x, sec = blockIdx.y;
    const int i0 = rt * 16;
    const int t = threadIdx.x, lane = t & 63, w = t >> 6;
    const int q = lane >> 4, n = lane & 15;
    const int m = t >> 5, jq = t & 31;
    const int ct = w >> 1, kf2 = w & 1;

    __shared__ u16 ersb[2048];
    __shared__ __align__(16) u16 pl[2][16][264];
    __shared__ unsigned absh[16][64];
    __shared__ float psum_sh[16];
    __shared__ float osh[4][16][16];
    __shared__ float wmax[8];
    __shared__ float mxsh;

    float4 a0 = *(const float4*)(er2p + t * 4);
    float4 a1 = *(const float4*)(er2p + NN + t * 4);
    float4 a2 = *(const float4*)(er2p + 2 * NN + t * 4);
    float4 a3 = *(const float4*)(er2p + 3 * NN + t * 4);
    float4 v0;
    v0.x = ((a0.x + a1.x) + (a2.x + a3.x));
    v0.y = ((a0.y + a1.y) + (a2.y + a3.y));
    v0.z = ((a0.z + a1.z) + (a2.z + a3.z));
    v0.w = ((a0.w + a1.w) + (a2.w + a3.w));
    uint2 c0;
    c0.x = pk2(v0.x, v0.y); c0.y = pk2(v0.z, v0.w);
    *(uint2*)&ersb[t * 4] = c0;
    float m0 = fmaxf(fmaxf(v0.x, v0.y), fmaxf(v0.z, v0.w));
#pragma unroll
    for (int off = 32; off; off >>= 1) m0 = fmaxf(m0, __shfl_xor(m0, off));
    if (lane == 0) wmax[w] = m0;
    for (int c = t; c < 1024; c += 512)
        absh[c >> 6][c & 63] = ab32[(size_t)(i0 + (c >> 6)) * 64 + (c & 63)];
    __syncthreads();
    if (t == 0) {
        float mm = wmax[0];
#pragma unroll
        for (int ww = 1; ww < 8; ++ww) mm = fmaxf(mm, wmax[ww]);
        mxsh = mm;
    }
    __syncthreads();

    const float elv = el2p[i0 + m] + el2p[NN + i0 + m] + el2p[2 * NN + i0 + m] + el2p[3 * NN + i0 + m];
    float mm2 = elv + mxsh;
    const float mxv = fmaxf(mm2, 0.2f * mm2);
    float ps = 0.f;

    auto stage = [&](int tl, int nb) {
#pragma unroll
        for (int sub = 0; sub < 2; ++sub) {
            unsigned word = absh[m][tl * 8 + sub * 4 + (jq >> 3)];
            unsigned bits = (word >> ((jq & 7) * 4)) & 0xFu;
            const int jo = tl * 256 + sub * 128 + jq * 4;
            uint2 raw = *(const uint2*)&ersb[jo];
            float e0 = __uint_as_float(raw.x << 16);
            float e1 = __uint_as_float(raw.x & 0xFFFF0000u);
            float e2 = __uint_as_float(raw.y << 16);
            float e3 = __uint_as_float(raw.y & 0xFFFF0000u);
            float s0 = elv + e0, s1 = elv + e1, s2 = elv + e2, s3 = elv + e3;
            s0 = fmaxf(s0, 0.2f * s0) - mxv;
            s1 = fmaxf(s1, 0.2f * s1) - mxv;
            s2 = fmaxf(s2, 0.2f * s2) - mxv;
            s3 = fmaxf(s3, 0.2f * s3) - mxv;
            float p0 = (bits & 1u) ? __expf(s0) : 0.f;
            float p1 = (bits & 2u) ? __expf(s1) : 0.f;
            float p2 = (bits & 4u) ? __expf(s2) : 0.f;
            float p3 = (bits & 8u) ? __expf(s3) : 0.f;
            ps += (p0 + p1) + (p2 + p3);
            uint2 pkv;
            pkv.x = pk2(p0, p1);
            pkv.y = pk2(p2, p3);
            *(uint2*)&pl[nb][m][sub * 128 + jq * 4] = pkv;
        }
    };

    const int col = sec * 64 + ct * 16 + n;
    const u16* gb = gbt + (size_t)col * NN + kf2 * 128 + q * 8;
    short8 bc0 = *(const short8*)gb;
    short8 bc1 = *(const short8*)(gb + 32);
    short8 bc2 = *(const short8*)(gb + 64);
    short8 bc3 = *(const short8*)(gb + 96);
    f32x4 acc = {0.f, 0.f, 0.f, 0.f};

    stage(0, 0);
    __syncthreads();

    for (int tile = 0; tile < 8; ++tile) {
        short8 bn0 = bc0, bn1 = bc1, bn2 = bc2, bn3 = bc3;
        if (tile < 7) {
            const u16* gq = gb + (tile + 1) * 256;
            bn0 = *(const short8*)gq;
            bn1 = *(const short8*)(gq + 32);
            bn2 = *(const short8*)(gq + 64);
            bn3 = *(const short8*)(gq + 96);
        }
        const u16* ap = &pl[tile & 1][n][kf2 * 128 + q * 8];
        short8 a0v = *(const short8*)ap;
        short8 a1v = *(const short8*)(ap + 32);
        short8 a2v = *(const short8*)(ap + 64);
        short8 a3v = *(const short8*)(ap + 96);
        acc = __builtin_amdgcn_mfma_f32_16x16x32_bf16(a0v, bc0, acc, 0, 0, 0);
        acc = __builtin_amdgcn_mfma_f32_16x16x32_bf16(a1v, bc1, acc, 0, 0, 0);
        acc = __builtin_amdgcn_mfma_f32_16x16x32_bf16(a2v, bc2, acc, 0, 0, 0);
        acc = __builtin_amdgcn_mfma_f32_16x16x32_bf16(a3v, bc3, acc, 0, 0, 0);
        if (tile < 7) stage(tile + 1, (tile + 1) & 1);
        bc0 = bn0; bc1 = bn1; bc2 = bn2; bc3 = bn3;
        __syncthreads();
    }

#pragma unroll
    for (int off = 16; off; off >>= 1) ps += __shfl_down(ps, off, 32);
    if (jq == 0) psum_sh[m] = ps;
    if (kf2 == 1) {
#pragma unroll
        for (int r = 0; r < 4; ++r) osh[ct][q * 4 + r][n] = acc[r];
    }
    __syncthreads();
    if (kf2 == 0) {
#pragma unroll
        for (int r = 0; r < 4; ++r) {
            int mr = q * 4 + r;
            out[(size_t)(i0 + mr) * 128 + col] = (acc[r] + osh[ct][mr][n]) / psum_sh[mr];
        }
    }
}

extern "C" void kernel_launch(void* const* d_in, const int* in_sizes, int n_in,
                              void* d_out, int out_size, void* d_ws, size_t ws_size,
                              hipStream_t stream) {
    const float* x   = (const float*)d_in[0];
    const float* W1  = (const float*)d_in[1];
    const float* a1l = (const float*)d_in[2];
    const float* a1r = (const float*)d_in[3];
    const float* W2  = (const float*)d_in[4];
    const float* a2l = (const float*)d_in[5];
    const float* a2r = (const float*)d_in[6];
    const int* adj = (const int*)d_in[7];

    char* p = (char*)d_ws;
    unsigned* abits = (unsigned*)p;  p += (size_t)NN * 64 * 4;
    u16* gbt1  = (u16*)p;            p += (size_t)256 * NN * 2;
    u16* hbb   = (u16*)p;            p += (size_t)NN * 256 * 2;
    u16* gbt2  = (u16*)p;            p += (size_t)128 * NN * 2;
    float* el1 = (float*)p;          p += (size_t)NN * 8 * 4;
    float* ert1 = (float*)p;         p += (size_t)8 * NN * 4;
    float* el2p = (float*)p;         p += (size_t)4 * NN * 4;
    float* er2p = (float*)p;         p += (size_t)4 * NN * 4;

    gemm1<<<dim3(128, 8), 256, 0, stream>>>(x, W1, adj, a1l, a1r, gbt1, el1, ert1, (u64*)abits);
    attn1<<<dim3(128, 4), 512, 0, stream>>>(el1, ert1, abits, gbt1, hbb);

    gemm2<<<dim3(128, 4), 256, 0, stream>>>(hbb, W2, a2l, a2r, gbt2, el2p, er2p);
    attn2<<<dim3(128, 2), 512, 0, stream>>>(el2p, er2p, abits, gbt2, (float*)d_out);
}